// Round 1
// baseline (2282.575 us; speedup 1.0000x reference)
//
#include <hip/hip_runtime.h>
#include <stdint.h>

typedef unsigned long long u64;

// ---------------- kernel 1: extract scores ----------------
__global__ void k_scores(const float* __restrict__ dets, float* __restrict__ sc, int n) {
    int i = blockIdx.x * blockDim.x + threadIdx.x;
    if (i < n) sc[i] = dets[i * 5 + 4];
}

// ---------------- kernel 2: rank (counting sort) + scatter sorted boxes ----------------
// one wave (64 lanes) per box i
__global__ void k_rank(const float* __restrict__ dets, const float* __restrict__ sc,
                       int* __restrict__ rank,
                       float* __restrict__ sx1, float* __restrict__ sy1,
                       float* __restrict__ sx2, float* __restrict__ sy2,
                       float* __restrict__ sarea, int n) {
    int gid  = blockIdx.x * blockDim.x + threadIdx.x;
    int wave = gid >> 6;
    int lane = threadIdx.x & 63;
    if (wave >= n) return;
    int i = wave;
    float si = sc[i];
    int cnt = 0;
    for (int j = lane; j < n; j += 64) {
        float sj = sc[j];
        cnt += (sj > si) || (sj == si && j < i);
    }
    for (int off = 32; off > 0; off >>= 1) cnt += __shfl_down(cnt, off, 64);
    if (lane == 0) {
        int r = cnt;
        rank[i] = r;
        float x1 = dets[i * 5 + 0], y1 = dets[i * 5 + 1];
        float x2 = dets[i * 5 + 2], y2 = dets[i * 5 + 3];
        sx1[r] = x1; sy1[r] = y1; sx2[r] = x2; sy2[r] = y2;
        sarea[r] = (x2 - x1 + 1.0f) * (y2 - y1 + 1.0f);
    }
}

// ---------------- kernel 3: suppression bit-matrix ----------------
// grid = nw*nw blocks of 64 threads; block (by,bx) computes words for rows
// by*64..by*64+63, column chunk bx. Lower-triangle word-blocks are written 0.
__global__ void k_mask(const float* __restrict__ sx1, const float* __restrict__ sy1,
                       const float* __restrict__ sx2, const float* __restrict__ sy2,
                       const float* __restrict__ sarea, const float* __restrict__ thrp,
                       u64* __restrict__ mask, int n, int nw) {
    int b  = blockIdx.x;
    int by = b / nw, bx = b % nw;
    int k  = threadIdx.x;           // 0..63
    int i  = by * 64 + k;           // row
    if (bx < by) { mask[(size_t)i * nw + bx] = 0ULL; return; }

    __shared__ float cx1[64], cy1[64], cx2[64], cy2[64], ca[64];
    int j0 = bx * 64;
    cx1[k] = sx1[j0 + k]; cy1[k] = sy1[j0 + k];
    cx2[k] = sx2[j0 + k]; cy2[k] = sy2[j0 + k];
    ca[k]  = sarea[j0 + k];
    __syncthreads();

    float x1 = sx1[i], y1 = sy1[i], x2 = sx2[i], y2 = sy2[i], ar = sarea[i];
    float thr = *thrp;
    u64 word = 0ULL;
    #pragma unroll 8
    for (int jj = 0; jj < 64; ++jj) {
        float xx1 = fmaxf(x1, cx1[jj]);
        float yy1 = fmaxf(y1, cy1[jj]);
        float xx2 = fminf(x2, cx2[jj]);
        float yy2 = fminf(y2, cy2[jj]);
        float w = fmaxf(xx2 - xx1 + 1.0f, 0.0f);
        float h = fmaxf(yy2 - yy1 + 1.0f, 0.0f);
        float inter = w * h;
        float iou = inter / (ar + ca[jj] - inter);   // same op order as reference
        word |= ((u64)(iou > thr)) << jj;
    }
    if (bx == by) word &= ~((2ULL << k) - 1ULL);     // keep only j > i
    mask[(size_t)i * nw + bx] = word;
}

// ---------------- kernel 4: serial greedy scan (single wave) ----------------
__global__ void k_scan(const u64* __restrict__ mask, u64* __restrict__ remv, int n, int nw) {
    int lane = threadIdx.x;   // 64 threads, 1 wave
    u64 r0 = 0ULL, r1 = 0ULL; // lane owns words [lane] and [64+lane]
    bool hi_valid = (64 + lane) < nw;
    for (int i = 0; i < n; ++i) {
        const u64* row = mask + (size_t)i * nw;
        u64 m0 = (lane < nw) ? row[lane] : 0ULL;
        u64 m1 = hi_valid ? row[64 + lane] : 0ULL;
        int word = i >> 6;
        u64 t0 = __shfl(r0, word & 63, 64);
        u64 t1 = __shfl(r1, word & 63, 64);
        u64 w  = (word < 64) ? t0 : t1;
        if (!((w >> (i & 63)) & 1ULL)) { r0 |= m0; r1 |= m1; }
    }
    if (lane < nw) remv[lane] = r0;
    if (hi_valid)  remv[64 + lane] = r1;
}

// ---------------- kernel 5: write output ----------------
__global__ void k_out(const float* __restrict__ dets, const int* __restrict__ rank,
                      const u64* __restrict__ remv, float* __restrict__ out, int n) {
    int idx = blockIdx.x * blockDim.x + threadIdx.x;
    if (idx >= n * 5) return;
    int i = idx / 5;
    int r = rank[i];
    u64 w = remv[r >> 6];
    float keep = ((w >> (r & 63)) & 1ULL) ? 0.0f : 1.0f;
    out[idx] = dets[idx] * keep;
}

extern "C" void kernel_launch(void* const* d_in, const int* in_sizes, int n_in,
                              void* d_out, int out_size, void* d_ws, size_t ws_size,
                              hipStream_t stream) {
    const float* dets = (const float*)d_in[0];
    const float* thrp = (const float*)d_in[1];
    int n  = in_sizes[0] / 5;
    int nw = (n + 63) / 64;

    char* ws = (char*)d_ws;
    size_t off = 0;
    u64* mask = (u64*)(ws + off);  off += (size_t)n * nw * sizeof(u64);
    float* sc    = (float*)(ws + off); off += (size_t)n * sizeof(float);
    int*   rank  = (int*)  (ws + off); off += (size_t)n * sizeof(int);
    float* sx1   = (float*)(ws + off); off += (size_t)n * sizeof(float);
    float* sy1   = (float*)(ws + off); off += (size_t)n * sizeof(float);
    float* sx2   = (float*)(ws + off); off += (size_t)n * sizeof(float);
    float* sy2   = (float*)(ws + off); off += (size_t)n * sizeof(float);
    float* sarea = (float*)(ws + off); off += (size_t)n * sizeof(float);
    u64* remv    = (u64*)  (ws + off); off += (size_t)nw * sizeof(u64);

    float* out = (float*)d_out;

    k_scores<<<(n + 255) / 256, 256, 0, stream>>>(dets, sc, n);
    k_rank<<<(n * 64 + 255) / 256, 256, 0, stream>>>(dets, sc, rank, sx1, sy1, sx2, sy2, sarea, n);
    k_mask<<<nw * nw, 64, 0, stream>>>(sx1, sy1, sx2, sy2, sarea, thrp, mask, n, nw);
    k_scan<<<1, 64, 0, stream>>>(mask, remv, n, nw);
    k_out<<<(n * 5 + 255) / 256, 256, 0, stream>>>(dets, rank, remv, out, n);
}

// Round 2
// 765.226 us; speedup vs baseline: 2.9829x; 2.9829x over previous
//
#include <hip/hip_runtime.h>
#include <stdint.h>

typedef unsigned long long u64;

// ---------------- kernel 1: extract scores ----------------
__global__ void k_scores(const float* __restrict__ dets, float* __restrict__ sc, int n) {
    int i = blockIdx.x * blockDim.x + threadIdx.x;
    if (i < n) sc[i] = dets[i * 5 + 4];
}

// ---------------- kernel 2: rank (counting sort) + scatter sorted boxes ----------------
// one wave (64 lanes) per box i
__global__ void k_rank(const float* __restrict__ dets, const float* __restrict__ sc,
                       int* __restrict__ rank,
                       float* __restrict__ sx1, float* __restrict__ sy1,
                       float* __restrict__ sx2, float* __restrict__ sy2,
                       float* __restrict__ sarea, int n) {
    int gid  = blockIdx.x * blockDim.x + threadIdx.x;
    int wave = gid >> 6;
    int lane = threadIdx.x & 63;
    if (wave >= n) return;
    int i = wave;
    float si = sc[i];
    int cnt = 0;
    for (int j = lane; j < n; j += 64) {
        float sj = sc[j];
        cnt += (sj > si) || (sj == si && j < i);
    }
    for (int off = 32; off > 0; off >>= 1) cnt += __shfl_down(cnt, off, 64);
    if (lane == 0) {
        int r = cnt;
        rank[i] = r;
        float x1 = dets[i * 5 + 0], y1 = dets[i * 5 + 1];
        float x2 = dets[i * 5 + 2], y2 = dets[i * 5 + 3];
        sx1[r] = x1; sy1[r] = y1; sx2[r] = x2; sy2[r] = y2;
        sarea[r] = (x2 - x1 + 1.0f) * (y2 - y1 + 1.0f);
    }
}

// ---------------- kernel 3: suppression bit-matrix ----------------
__global__ void k_mask(const float* __restrict__ sx1, const float* __restrict__ sy1,
                       const float* __restrict__ sx2, const float* __restrict__ sy2,
                       const float* __restrict__ sarea, const float* __restrict__ thrp,
                       u64* __restrict__ mask, int n, int nw) {
    int b  = blockIdx.x;
    int by = b / nw, bx = b % nw;
    int k  = threadIdx.x;           // 0..63
    int i  = by * 64 + k;           // row
    if (bx < by) { mask[(size_t)i * nw + bx] = 0ULL; return; }

    __shared__ float cx1[64], cy1[64], cx2[64], cy2[64], ca[64];
    int j0 = bx * 64;
    cx1[k] = sx1[j0 + k]; cy1[k] = sy1[j0 + k];
    cx2[k] = sx2[j0 + k]; cy2[k] = sy2[j0 + k];
    ca[k]  = sarea[j0 + k];
    __syncthreads();

    float x1 = sx1[i], y1 = sy1[i], x2 = sx2[i], y2 = sy2[i], ar = sarea[i];
    float thr = *thrp;
    u64 word = 0ULL;
    #pragma unroll 8
    for (int jj = 0; jj < 64; ++jj) {
        float xx1 = fmaxf(x1, cx1[jj]);
        float yy1 = fmaxf(y1, cy1[jj]);
        float xx2 = fminf(x2, cx2[jj]);
        float yy2 = fminf(y2, cy2[jj]);
        float w = fmaxf(xx2 - xx1 + 1.0f, 0.0f);
        float h = fmaxf(yy2 - yy1 + 1.0f, 0.0f);
        float inter = w * h;
        float iou = inter / (ar + ca[jj] - inter);   // same op order as reference
        word |= ((u64)(iou > thr)) << jj;
    }
    if (bx == by) word &= ~((2ULL << k) - 1ULL);     // keep only j > i
    mask[(size_t)i * nw + bx] = word;
}

// ---------------- helper: readlane of a u64 (lane must be compile-time uniform) ----------------
__device__ __forceinline__ u64 readlane_u64(u64 v, int lane) {
    unsigned lo = (unsigned)__builtin_amdgcn_readlane((int)(v & 0xffffffffu), lane);
    unsigned hi = (unsigned)__builtin_amdgcn_readlane((int)(v >> 32), lane);
    return ((u64)hi << 32) | lo;
}

// ---------------- kernel 4: blocked greedy scan (single wave) ----------------
// remv (128 words max) lives in registers: lane owns words [lane] and [64+lane].
// Per 64-row block: scalar-unit serial resolve of the diagonal, then batched
// pipelined bulk-OR of alive rows' future words.
__global__ void k_scan(const u64* __restrict__ mask, u64* __restrict__ remv, int n, int nw) {
    int lane = threadIdx.x;   // 64 threads, 1 wave
    u64 r0 = 0ULL, r1 = 0ULL;
    int nb = nw;              // number of 64-row blocks == number of words

    // prefetch diag for block 0: lane k holds mask[k][0]
    u64 diag = mask[(size_t)lane * nw + 0];

    for (int b = 0; b < nb; ++b) {
        // prefetch next block's diagonal (independent of everything below)
        u64 diag_next = 0ULL;
        if (b + 1 < nb)
            diag_next = mask[(size_t)((b + 1) * 64 + lane) * nw + (b + 1)];

        // current remv word for this block (uniform, scalar)
        int owner = b & 63;
        u64 cur = (b < 64) ? r0 : r1;
        u64 w = readlane_u64(cur, owner);

        // ---- serial greedy resolve of the 64x64 diagonal, on the scalar unit ----
        #pragma unroll
        for (int k = 0; k < 64; ++k) {
            u64 dk = readlane_u64(diag, k);          // prefetchable, independent of w
            if (!((w >> k) & 1ULL)) w |= dk;         // scalar chain: test/select/or
        }

        // write resolved word back into the owner lane's register
        if (lane == owner) { if (b < 64) r0 = w; else r1 = w; }

        // ---- bulk OR: alive rows' words for columns > b ----
        const u64* rowbase = mask + (size_t)(b * 64) * nw;
        bool c0 = (lane > b) && (lane < nw);             // r0 word index = lane
        bool c1 = (64 + lane > b) && (64 + lane < nw);   // r1 word index = 64+lane
        #pragma unroll 1
        for (int k0 = 0; k0 < 64; k0 += 16) {
            u64 a0[16], a1[16];
            #pragma unroll
            for (int t = 0; t < 16; ++t) {
                int k = k0 + t;
                bool alive = !((w >> k) & 1ULL);          // uniform
                const u64* row = rowbase + (size_t)k * nw;
                a0[t] = (alive && c0) ? row[lane] : 0ULL;
                a1[t] = (alive && c1) ? row[64 + lane] : 0ULL;
            }
            #pragma unroll
            for (int t = 0; t < 16; ++t) { r0 |= a0[t]; r1 |= a1[t]; }
        }

        diag = diag_next;
    }

    if (lane < nw) remv[lane] = r0;
    if (64 + lane < nw) remv[64 + lane] = r1;
}

// ---------------- kernel 5: write output ----------------
__global__ void k_out(const float* __restrict__ dets, const int* __restrict__ rank,
                      const u64* __restrict__ remv, float* __restrict__ out, int n) {
    int idx = blockIdx.x * blockDim.x + threadIdx.x;
    if (idx >= n * 5) return;
    int i = idx / 5;
    int r = rank[i];
    u64 w = remv[r >> 6];
    float keep = ((w >> (r & 63)) & 1ULL) ? 0.0f : 1.0f;
    out[idx] = dets[idx] * keep;
}

extern "C" void kernel_launch(void* const* d_in, const int* in_sizes, int n_in,
                              void* d_out, int out_size, void* d_ws, size_t ws_size,
                              hipStream_t stream) {
    const float* dets = (const float*)d_in[0];
    const float* thrp = (const float*)d_in[1];
    int n  = in_sizes[0] / 5;
    int nw = (n + 63) / 64;

    char* ws = (char*)d_ws;
    size_t off = 0;
    u64* mask = (u64*)(ws + off);  off += (size_t)n * nw * sizeof(u64);
    float* sc    = (float*)(ws + off); off += (size_t)n * sizeof(float);
    int*   rank  = (int*)  (ws + off); off += (size_t)n * sizeof(int);
    float* sx1   = (float*)(ws + off); off += (size_t)n * sizeof(float);
    float* sy1   = (float*)(ws + off); off += (size_t)n * sizeof(float);
    float* sx2   = (float*)(ws + off); off += (size_t)n * sizeof(float);
    float* sy2   = (float*)(ws + off); off += (size_t)n * sizeof(float);
    float* sarea = (float*)(ws + off); off += (size_t)n * sizeof(float);
    u64* remv    = (u64*)  (ws + off); off += (size_t)nw * sizeof(u64);

    float* out = (float*)d_out;

    k_scores<<<(n + 255) / 256, 256, 0, stream>>>(dets, sc, n);
    k_rank<<<(n * 64 + 255) / 256, 256, 0, stream>>>(dets, sc, rank, sx1, sy1, sx2, sy2, sarea, n);
    k_mask<<<nw * nw, 64, 0, stream>>>(sx1, sy1, sx2, sy2, sarea, thrp, mask, n, nw);
    k_scan<<<1, 64, 0, stream>>>(mask, remv, n, nw);
    k_out<<<(n * 5 + 255) / 256, 256, 0, stream>>>(dets, rank, remv, out, n);
}

// Round 3
// 554.143 us; speedup vs baseline: 4.1191x; 1.3809x over previous
//
#include <hip/hip_runtime.h>
#include <stdint.h>

typedef unsigned long long u64;

// ---------------- kernel 1: extract scores ----------------
__global__ void k_scores(const float* __restrict__ dets, float* __restrict__ sc, int n) {
    int i = blockIdx.x * blockDim.x + threadIdx.x;
    if (i < n) sc[i] = dets[i * 5 + 4];
}

// ---------------- kernel 2: rank (counting sort) + scatter sorted boxes ----------------
// one wave (64 lanes) per box i
__global__ void k_rank(const float* __restrict__ dets, const float* __restrict__ sc,
                       int* __restrict__ rank,
                       float* __restrict__ sx1, float* __restrict__ sy1,
                       float* __restrict__ sx2, float* __restrict__ sy2,
                       float* __restrict__ sarea, int n) {
    int gid  = blockIdx.x * blockDim.x + threadIdx.x;
    int wave = gid >> 6;
    int lane = threadIdx.x & 63;
    if (wave >= n) return;
    int i = wave;
    float si = sc[i];
    int cnt = 0;
    for (int j = lane; j < n; j += 64) {
        float sj = sc[j];
        cnt += (sj > si) || (sj == si && j < i);
    }
    for (int off = 32; off > 0; off >>= 1) cnt += __shfl_down(cnt, off, 64);
    if (lane == 0) {
        int r = cnt;
        rank[i] = r;
        float x1 = dets[i * 5 + 0], y1 = dets[i * 5 + 1];
        float x2 = dets[i * 5 + 2], y2 = dets[i * 5 + 3];
        sx1[r] = x1; sy1[r] = y1; sx2[r] = x2; sy2[r] = y2;
        sarea[r] = (x2 - x1 + 1.0f) * (y2 - y1 + 1.0f);
    }
}

// ---------------- kernel 3: suppression bit-matrix ----------------
__global__ void k_mask(const float* __restrict__ sx1, const float* __restrict__ sy1,
                       const float* __restrict__ sx2, const float* __restrict__ sy2,
                       const float* __restrict__ sarea, const float* __restrict__ thrp,
                       u64* __restrict__ mask, int n, int nw) {
    int b  = blockIdx.x;
    int by = b / nw, bx = b % nw;
    int k  = threadIdx.x;           // 0..63
    int i  = by * 64 + k;           // row
    if (bx < by) { mask[(size_t)i * nw + bx] = 0ULL; return; }

    __shared__ float cx1[64], cy1[64], cx2[64], cy2[64], ca[64];
    int j0 = bx * 64;
    cx1[k] = sx1[j0 + k]; cy1[k] = sy1[j0 + k];
    cx2[k] = sx2[j0 + k]; cy2[k] = sy2[j0 + k];
    ca[k]  = sarea[j0 + k];
    __syncthreads();

    float x1 = sx1[i], y1 = sy1[i], x2 = sx2[i], y2 = sy2[i], ar = sarea[i];
    float thr = *thrp;
    u64 word = 0ULL;
    #pragma unroll 8
    for (int jj = 0; jj < 64; ++jj) {
        float xx1 = fmaxf(x1, cx1[jj]);
        float yy1 = fmaxf(y1, cy1[jj]);
        float xx2 = fminf(x2, cx2[jj]);
        float yy2 = fminf(y2, cy2[jj]);
        float w = fmaxf(xx2 - xx1 + 1.0f, 0.0f);
        float h = fmaxf(yy2 - yy1 + 1.0f, 0.0f);
        float inter = w * h;
        float iou = inter / (ar + ca[jj] - inter);   // same op order as reference
        word |= ((u64)(iou > thr)) << jj;
    }
    if (bx == by) word &= ~((2ULL << k) - 1ULL);     // keep only j > i
    mask[(size_t)i * nw + bx] = word;
}

// ---------------- helper: readlane of a u64 (lane must be compile-time uniform) ----------------
__device__ __forceinline__ u64 readlane_u64(u64 v, int lane) {
    unsigned lo = (unsigned)__builtin_amdgcn_readlane((int)(v & 0xffffffffu), lane);
    unsigned hi = (unsigned)__builtin_amdgcn_readlane((int)(v >> 32), lane);
    return ((u64)hi << 32) | lo;
}

// ---------------- kernel 4: blocked greedy scan (1 workgroup, 16 waves) ----------------
// remv lives in LDS (nw <= 128 words). Per 64-row block:
//   - wave 0: serial scalar-chain resolve of the 64x64 diagonal
//   - all 16 waves: bulk-OR of alive rows' future words into lds_remv
//     thread layout: row-octet = wave>>1 (uniform alive predicate per wave),
//     column = b+1 + (t&127)  (lane-contiguous -> coalesced 512B per row-load)
__launch_bounds__(1024, 1)
__global__ void k_scan(const u64* __restrict__ mask, u64* __restrict__ remv, int n, int nw) {
    __shared__ u64 lds_remv[128];
    __shared__ u64 lds_w;
    int t    = threadIdx.x;
    int lane = t & 63;
    int wave = t >> 6;
    int rg   = t >> 7;     // row octet 0..7 (uniform per wave)
    int cl   = t & 127;    // column offset 0..127

    if (t < 128) lds_remv[t] = 0ULL;

    // wave 0: prefetch diagonal of block 0 (lane k holds mask[k][0])
    u64 diag = 0ULL;
    if (wave == 0) diag = mask[(size_t)lane * nw + 0];
    __syncthreads();

    int nb = nw;
    for (int b = 0; b < nb; ++b) {
        // ---- serial greedy resolve of the diagonal (wave 0, scalar chain) ----
        if (wave == 0) {
            u64 w = lds_remv[b];
            #pragma unroll
            for (int k = 0; k < 64; ++k) {
                u64 dk = readlane_u64(diag, k);
                if (!((w >> k) & 1ULL)) w |= dk;
            }
            if (lane == 0) { lds_w = w; lds_remv[b] = w; }
        }
        __syncthreads();
        u64 w = lds_w;

        // prefetch next block's diagonal (wave 0) — overlaps bulk-OR loads
        u64 diag_next = 0ULL;
        if (wave == 0 && b + 1 < nb)
            diag_next = mask[(size_t)((b + 1) * 64 + lane) * nw + (b + 1)];

        // ---- bulk OR: alive rows' words for columns > b ----
        int c = b + 1 + cl;
        u64 acc = 0ULL;
        if (c < nw) {
            const u64* base = mask + (size_t)(b * 64 + rg * 8) * nw + c;
            #pragma unroll
            for (int u = 0; u < 8; ++u) {
                int k = rg * 8 + u;
                if (!((w >> k) & 1ULL))            // wave-uniform predicate
                    acc |= base[(size_t)u * nw];
            }
        }
        if (c < nw && acc) atomicOr(&lds_remv[c], acc);
        __syncthreads();

        diag = diag_next;
    }

    if (t < nw) remv[t] = lds_remv[t];
}

// ---------------- kernel 5: write output ----------------
__global__ void k_out(const float* __restrict__ dets, const int* __restrict__ rank,
                      const u64* __restrict__ remv, float* __restrict__ out, int n) {
    int idx = blockIdx.x * blockDim.x + threadIdx.x;
    if (idx >= n * 5) return;
    int i = idx / 5;
    int r = rank[i];
    u64 w = remv[r >> 6];
    float keep = ((w >> (r & 63)) & 1ULL) ? 0.0f : 1.0f;
    out[idx] = dets[idx] * keep;
}

extern "C" void kernel_launch(void* const* d_in, const int* in_sizes, int n_in,
                              void* d_out, int out_size, void* d_ws, size_t ws_size,
                              hipStream_t stream) {
    const float* dets = (const float*)d_in[0];
    const float* thrp = (const float*)d_in[1];
    int n  = in_sizes[0] / 5;
    int nw = (n + 63) / 64;

    char* ws = (char*)d_ws;
    size_t off = 0;
    u64* mask = (u64*)(ws + off);  off += (size_t)n * nw * sizeof(u64);
    float* sc    = (float*)(ws + off); off += (size_t)n * sizeof(float);
    int*   rank  = (int*)  (ws + off); off += (size_t)n * sizeof(int);
    float* sx1   = (float*)(ws + off); off += (size_t)n * sizeof(float);
    float* sy1   = (float*)(ws + off); off += (size_t)n * sizeof(float);
    float* sx2   = (float*)(ws + off); off += (size_t)n * sizeof(float);
    float* sy2   = (float*)(ws + off); off += (size_t)n * sizeof(float);
    float* sarea = (float*)(ws + off); off += (size_t)n * sizeof(float);
    u64* remv    = (u64*)  (ws + off); off += (size_t)nw * sizeof(u64);

    float* out = (float*)d_out;

    k_scores<<<(n + 255) / 256, 256, 0, stream>>>(dets, sc, n);
    k_rank<<<(n * 64 + 255) / 256, 256, 0, stream>>>(dets, sc, rank, sx1, sy1, sx2, sy2, sarea, n);
    k_mask<<<nw * nw, 64, 0, stream>>>(sx1, sy1, sx2, sy2, sarea, thrp, mask, n, nw);
    k_scan<<<1, 1024, 0, stream>>>(mask, remv, n, nw);
    k_out<<<(n * 5 + 255) / 256, 256, 0, stream>>>(dets, rank, remv, out, n);
}

// Round 4
// 540.690 us; speedup vs baseline: 4.2216x; 1.0249x over previous
//
#include <hip/hip_runtime.h>
#include <stdint.h>

typedef unsigned long long u64;

// ---------------- kernel 1: extract scores ----------------
__global__ void k_scores(const float* __restrict__ dets, float* __restrict__ sc, int n) {
    int i = blockIdx.x * blockDim.x + threadIdx.x;
    if (i < n) sc[i] = dets[i * 5 + 4];
}

// ---------------- kernel 2: rank (counting sort) + scatter sorted boxes ----------------
// one wave (64 lanes) per box i
__global__ void k_rank(const float* __restrict__ dets, const float* __restrict__ sc,
                       int* __restrict__ rank,
                       float* __restrict__ sx1, float* __restrict__ sy1,
                       float* __restrict__ sx2, float* __restrict__ sy2,
                       float* __restrict__ sarea, int n) {
    int gid  = blockIdx.x * blockDim.x + threadIdx.x;
    int wave = gid >> 6;
    int lane = threadIdx.x & 63;
    if (wave >= n) return;
    int i = wave;
    float si = sc[i];
    int cnt = 0;
    for (int j = lane; j < n; j += 64) {
        float sj = sc[j];
        cnt += (sj > si) || (sj == si && j < i);
    }
    for (int off = 32; off > 0; off >>= 1) cnt += __shfl_down(cnt, off, 64);
    if (lane == 0) {
        int r = cnt;
        rank[i] = r;
        float x1 = dets[i * 5 + 0], y1 = dets[i * 5 + 1];
        float x2 = dets[i * 5 + 2], y2 = dets[i * 5 + 3];
        sx1[r] = x1; sy1[r] = y1; sx2[r] = x2; sy2[r] = y2;
        sarea[r] = (x2 - x1 + 1.0f) * (y2 - y1 + 1.0f);
    }
}

// ---------------- kernel 3: suppression bit-matrix ----------------
__global__ void k_mask(const float* __restrict__ sx1, const float* __restrict__ sy1,
                       const float* __restrict__ sx2, const float* __restrict__ sy2,
                       const float* __restrict__ sarea, const float* __restrict__ thrp,
                       u64* __restrict__ mask, int n, int nw) {
    int b  = blockIdx.x;
    int by = b / nw, bx = b % nw;
    int k  = threadIdx.x;           // 0..63
    int i  = by * 64 + k;           // row
    if (bx < by) { mask[(size_t)i * nw + bx] = 0ULL; return; }

    __shared__ float cx1[64], cy1[64], cx2[64], cy2[64], ca[64];
    int j0 = bx * 64;
    cx1[k] = sx1[j0 + k]; cy1[k] = sy1[j0 + k];
    cx2[k] = sx2[j0 + k]; cy2[k] = sy2[j0 + k];
    ca[k]  = sarea[j0 + k];
    __syncthreads();

    float x1 = sx1[i], y1 = sy1[i], x2 = sx2[i], y2 = sy2[i], ar = sarea[i];
    float thr = *thrp;
    u64 word = 0ULL;
    #pragma unroll 8
    for (int jj = 0; jj < 64; ++jj) {
        float xx1 = fmaxf(x1, cx1[jj]);
        float yy1 = fmaxf(y1, cy1[jj]);
        float xx2 = fminf(x2, cx2[jj]);
        float yy2 = fminf(y2, cy2[jj]);
        float w = fmaxf(xx2 - xx1 + 1.0f, 0.0f);
        float h = fmaxf(yy2 - yy1 + 1.0f, 0.0f);
        float inter = w * h;
        float iou = inter / (ar + ca[jj] - inter);   // same op order as reference
        word |= ((u64)(iou > thr)) << jj;
    }
    if (bx == by) word &= ~((2ULL << k) - 1ULL);     // keep only j > i
    mask[(size_t)i * nw + bx] = word;
}

// ---------------- helper: readlane of a u64 (runtime lane index ok) ----------------
__device__ __forceinline__ u64 readlane_u64(u64 v, int lane) {
    unsigned lo = (unsigned)__builtin_amdgcn_readlane((int)(v & 0xffffffffu), lane);
    unsigned hi = (unsigned)__builtin_amdgcn_readlane((int)(v >> 32), lane);
    return ((u64)hi << 32) | lo;
}

// ---------------- kernel 4: blocked greedy scan (1 workgroup, 16 waves) ----------------
// remv lives in LDS (nw <= 128 words). Per 64-row block:
//   - wave 0: ctz-driven serial resolve of the 64x64 diagonal (alive rows only)
//   - all 16 waves: bulk-OR with UNCONDITIONAL independent loads (8/thread in
//     flight, single waitcnt), masked by per-row alive select. Latency-pipelined.
__launch_bounds__(1024, 1)
__global__ void k_scan(const u64* __restrict__ mask, u64* __restrict__ remv, int n, int nw) {
    __shared__ u64 lds_remv[128];
    __shared__ u64 lds_w;
    int t    = threadIdx.x;
    int lane = t & 63;
    int wave = t >> 6;
    int rg   = t >> 7;     // row octet 0..7 (uniform per wave)
    int cl   = t & 127;    // column offset 0..127

    if (t < 128) lds_remv[t] = 0ULL;

    // wave 0: prefetch diagonal of block 0 (lane k holds mask[k][0])
    u64 diag = 0ULL;
    if (wave == 0) diag = mask[(size_t)lane * nw + 0];
    __syncthreads();

    int nb = nw;
    for (int b = 0; b < nb; ++b) {
        // ---- serial greedy resolve of the diagonal (wave 0, alive-bits only) ----
        if (wave == 0) {
            u64 w = lds_remv[b];
            u64 avail = ~w;                         // candidate alive rows
            while (avail) {
                int k = __builtin_ctzll(avail);     // lowest alive row -> ascending order
                u64 dk = readlane_u64(diag, k);     // diag row k (bits j>k only)
                w |= dk;
                avail &= ~(w | (1ULL << k));        // drop suppressed + processed
            }
            if (lane == 0) { lds_w = w; lds_remv[b] = w; }
        }
        __syncthreads();
        u64 w = lds_w;

        // prefetch next block's diagonal (wave 0) — overlaps bulk-OR loads
        u64 diag_next = 0ULL;
        if (wave == 0 && b + 1 < nb)
            diag_next = mask[(size_t)((b + 1) * 64 + lane) * nw + (b + 1)];

        // ---- bulk OR: 8 unconditional independent loads, then masked OR ----
        int c  = b + 1 + cl;
        bool cv = (c < nw);
        int cc = cv ? c : b;                        // clamp to a valid word
        const u64* base = mask + (size_t)(b * 64 + rg * 8) * nw + cc;
        unsigned alive8 = (unsigned)((~w) >> (rg * 8)) & 0xffu;

        u64 a[8];
        #pragma unroll
        for (int u = 0; u < 8; ++u)
            a[u] = base[(size_t)u * nw];            // independent, all in flight
        u64 acc = 0ULL;
        #pragma unroll
        for (int u = 0; u < 8; ++u) {
            u64 sel = (u64)0 - (u64)((alive8 >> u) & 1u);
            acc |= a[u] & sel;
        }
        if (cv && acc) atomicOr(&lds_remv[c], acc);
        __syncthreads();

        diag = diag_next;
    }

    if (t < nw) remv[t] = lds_remv[t];
}

// ---------------- kernel 5: write output ----------------
__global__ void k_out(const float* __restrict__ dets, const int* __restrict__ rank,
                      const u64* __restrict__ remv, float* __restrict__ out, int n) {
    int idx = blockIdx.x * blockDim.x + threadIdx.x;
    if (idx >= n * 5) return;
    int i = idx / 5;
    int r = rank[i];
    u64 w = remv[r >> 6];
    float keep = ((w >> (r & 63)) & 1ULL) ? 0.0f : 1.0f;
    out[idx] = dets[idx] * keep;
}

extern "C" void kernel_launch(void* const* d_in, const int* in_sizes, int n_in,
                              void* d_out, int out_size, void* d_ws, size_t ws_size,
                              hipStream_t stream) {
    const float* dets = (const float*)d_in[0];
    const float* thrp = (const float*)d_in[1];
    int n  = in_sizes[0] / 5;
    int nw = (n + 63) / 64;

    char* ws = (char*)d_ws;
    size_t off = 0;
    u64* mask = (u64*)(ws + off);  off += (size_t)n * nw * sizeof(u64);
    float* sc    = (float*)(ws + off); off += (size_t)n * sizeof(float);
    int*   rank  = (int*)  (ws + off); off += (size_t)n * sizeof(int);
    float* sx1   = (float*)(ws + off); off += (size_t)n * sizeof(float);
    float* sy1   = (float*)(ws + off); off += (size_t)n * sizeof(float);
    float* sx2   = (float*)(ws + off); off += (size_t)n * sizeof(float);
    float* sy2   = (float*)(ws + off); off += (size_t)n * sizeof(float);
    float* sarea = (float*)(ws + off); off += (size_t)n * sizeof(float);
    u64* remv    = (u64*)  (ws + off); off += (size_t)nw * sizeof(u64);

    float* out = (float*)d_out;

    k_scores<<<(n + 255) / 256, 256, 0, stream>>>(dets, sc, n);
    k_rank<<<(n * 64 + 255) / 256, 256, 0, stream>>>(dets, sc, rank, sx1, sy1, sx2, sy2, sarea, n);
    k_mask<<<nw * nw, 64, 0, stream>>>(sx1, sy1, sx2, sy2, sarea, thrp, mask, n, nw);
    k_scan<<<1, 1024, 0, stream>>>(mask, remv, n, nw);
    k_out<<<(n * 5 + 255) / 256, 256, 0, stream>>>(dets, rank, remv, out, n);
}

// Round 5
// 167.293 us; speedup vs baseline: 13.6442x; 3.2320x over previous
//
#include <hip/hip_runtime.h>
#include <stdint.h>

typedef unsigned long long u64;
typedef unsigned int u32;

#define ENT_CAP 16384      // entries per 64-row block: 128*16384*4 = 8 MB
#define LDS_ENT_CAP 4096   // per-group LDS staging capacity
#define GRP 16             // blocks per group in k_scan

// ---------------- kernel 1: extract scores + zero entry counters ----------------
__global__ void k_scores(const float* __restrict__ dets, float* __restrict__ sc,
                         int* __restrict__ cnt, int n) {
    int i = blockIdx.x * blockDim.x + threadIdx.x;
    if (i < n) sc[i] = dets[i * 5 + 4];
    if (i < 128) cnt[i] = 0;
}

// ---------------- kernel 2: rank (counting sort) + scatter sorted boxes ----------------
__global__ void k_rank(const float* __restrict__ dets, const float* __restrict__ sc,
                       int* __restrict__ rank,
                       float* __restrict__ sx1, float* __restrict__ sy1,
                       float* __restrict__ sx2, float* __restrict__ sy2,
                       float* __restrict__ sarea, int n) {
    int gid  = blockIdx.x * blockDim.x + threadIdx.x;
    int wave = gid >> 6;
    int lane = threadIdx.x & 63;
    if (wave >= n) return;
    int i = wave;
    float si = sc[i];
    int cnt = 0;
    for (int j = lane; j < n; j += 64) {
        float sj = sc[j];
        cnt += (sj > si) || (sj == si && j < i);
    }
    for (int off = 32; off > 0; off >>= 1) cnt += __shfl_down(cnt, off, 64);
    if (lane == 0) {
        int r = cnt;
        rank[i] = r;
        float x1 = dets[i * 5 + 0], y1 = dets[i * 5 + 1];
        float x2 = dets[i * 5 + 2], y2 = dets[i * 5 + 3];
        sx1[r] = x1; sy1[r] = y1; sx2[r] = x2; sy2[r] = y2;
        sarea[r] = (x2 - x1 + 1.0f) * (y2 - y1 + 1.0f);
    }
}

// ---------------- kernel 3: sparse suppression graph ----------------
// diag[i]   : 64x64 in-block conflict bits (j>i only) for row-block i/64
// ent[b][.] : (k<<16 | j) conflict entries, k = row local to block b, j global col
__global__ void k_mask(const float* __restrict__ sx1, const float* __restrict__ sy1,
                       const float* __restrict__ sx2, const float* __restrict__ sy2,
                       const float* __restrict__ sarea, const float* __restrict__ thrp,
                       u64* __restrict__ diag, u32* __restrict__ ent, int* __restrict__ cnt,
                       int n, int nw) {
    int b  = blockIdx.x;
    int by = b / nw, bx = b % nw;
    if (bx < by) return;                 // lower triangle: nothing to do
    int k  = threadIdx.x;                // 0..63
    int i  = by * 64 + k;                // global row

    __shared__ float cx1[64], cy1[64], cx2[64], cy2[64], ca[64];
    int j0 = bx * 64;
    cx1[k] = sx1[j0 + k]; cy1[k] = sy1[j0 + k];
    cx2[k] = sx2[j0 + k]; cy2[k] = sy2[j0 + k];
    ca[k]  = sarea[j0 + k];
    __syncthreads();

    float x1 = sx1[i], y1 = sy1[i], x2 = sx2[i], y2 = sy2[i], ar = sarea[i];
    float thr = *thrp;
    u64 word = 0ULL;
    #pragma unroll 8
    for (int jj = 0; jj < 64; ++jj) {
        float xx1 = fmaxf(x1, cx1[jj]);
        float yy1 = fmaxf(y1, cy1[jj]);
        float xx2 = fminf(x2, cx2[jj]);
        float yy2 = fminf(y2, cy2[jj]);
        float w = fmaxf(xx2 - xx1 + 1.0f, 0.0f);
        float h = fmaxf(yy2 - yy1 + 1.0f, 0.0f);
        float inter = w * h;
        float iou = inter / (ar + ca[jj] - inter);   // same op order as reference
        word |= ((u64)(iou > thr)) << jj;
    }

    if (bx == by) {
        word &= ~((2ULL << k) - 1ULL);   // keep only j > i
        diag[i] = word;                  // always write (replay-safe)
        return;
    }
    if (__ballot(word != 0ULL) == 0ULL) return;   // whole block conflict-free
    int pc = __popcll(word);
    if (pc) {
        int base = atomicAdd(&cnt[by], pc);
        u32* dst = ent + (size_t)by * ENT_CAP;
        u64 ww = word;
        int x = 0;
        while (ww) {
            int jj = __builtin_ctzll(ww); ww &= ww - 1;
            int idx = base + x;
            if (idx < ENT_CAP) dst[idx] = ((u32)k << 16) | (u32)(j0 + jj);
            ++x;
        }
    }
}

// ---------------- helper: readlane of a u64 (uniform runtime lane index) ----------------
__device__ __forceinline__ u64 readlane_u64(u64 v, int lane) {
    unsigned lo = (unsigned)__builtin_amdgcn_readlane((int)(v & 0xffffffffu), lane);
    unsigned hi = (unsigned)__builtin_amdgcn_readlane((int)(v >> 32), lane);
    return ((u64)hi << 32) | lo;
}

// ---------------- kernel 4: sparse greedy scan (1 workgroup, 4 waves) ----------------
__launch_bounds__(256, 1)
__global__ void k_scan(const u64* __restrict__ diag, const u32* __restrict__ ent,
                       const int* __restrict__ cnt, u64* __restrict__ remv,
                       int n, int nw) {
    __shared__ u64 lds_remv[128];
    __shared__ u64 lds_diag[GRP * 64];
    __shared__ u32 lds_ent[LDS_ENT_CAP];
    __shared__ int lds_cnt[128];
    __shared__ int lds_ofs[GRP + 1];
    __shared__ u64 lds_w;
    __shared__ int lds_glob;

    int t    = threadIdx.x;
    int lane = t & 63;
    int wave = t >> 6;

    if (t < 128) {
        lds_remv[t] = 0ULL;
        lds_cnt[t]  = (t < nw) ? min(cnt[t], ENT_CAP) : 0;
    }
    __syncthreads();

    for (int g0 = 0; g0 < nw; g0 += GRP) {
        int gcnt = min(GRP, nw - g0);
        if (t == 0) {
            int s = 0;
            for (int u = 0; u < gcnt; ++u) { lds_ofs[u] = s; s += lds_cnt[g0 + u]; }
            lds_ofs[gcnt] = s;
            lds_glob = (s > LDS_ENT_CAP) ? 1 : 0;
        }
        __syncthreads();
        int use_glob = lds_glob;

        // stage this group's entries + diagonals into LDS
        if (!use_glob) {
            for (int u = 0; u < gcnt; ++u) {
                int cb = lds_cnt[g0 + u], o = lds_ofs[u];
                const u32* src = ent + (size_t)(g0 + u) * ENT_CAP;
                for (int idx = t; idx < cb; idx += 256) lds_ent[o + idx] = src[idx];
            }
        }
        for (int idx = t; idx < gcnt * 64; idx += 256)
            lds_diag[idx] = diag[g0 * 64 + idx];
        __syncthreads();

        u64 dreg = (wave == 0) ? lds_diag[lane] : 0ULL;

        for (int bb = 0; bb < gcnt; ++bb) {
            int b = g0 + bb;
            // ---- greedy resolve of the 64x64 diagonal (wave 0) ----
            if (wave == 0) {
                u64 w  = lds_remv[b];
                u64 nz = __ballot(dreg != 0ULL);       // rows with any in-block conflict
                u64 avail = ~w & nz;
                while (avail) {
                    int k = __builtin_ctzll(avail);
                    w |= readlane_u64(dreg, k);
                    avail &= ~(w | (1ULL << k));
                }
                if (lane == 0) lds_w = w;
            }
            __syncthreads();
            u64 w = lds_w;
            if (t == 0) lds_remv[b] = w;               // finalize this word
            // prefetch next diagonal rows (LDS, hidden under apply)
            u64 dreg_next = (wave == 0 && bb + 1 < gcnt) ? lds_diag[(bb + 1) * 64 + lane] : 0ULL;

            // ---- scatter alive rows' entries ----
            int cb = lds_cnt[b];
            if (!use_glob) {
                int o = lds_ofs[bb];
                for (int idx = t; idx < cb; idx += 256) {
                    u32 e = lds_ent[o + idx];
                    int k = e >> 16, j = e & 0xffff;
                    if (!((w >> k) & 1ULL))
                        atomicOr(&lds_remv[j >> 6], 1ULL << (j & 63));
                }
            } else {
                const u32* src = ent + (size_t)b * ENT_CAP;
                for (int idx = t; idx < cb; idx += 256) {
                    u32 e = src[idx];
                    int k = e >> 16, j = e & 0xffff;
                    if (!((w >> k) & 1ULL))
                        atomicOr(&lds_remv[j >> 6], 1ULL << (j & 63));
                }
            }
            __syncthreads();
            dreg = dreg_next;
        }
    }

    if (t < nw) remv[t] = lds_remv[t];
}

// ---------------- kernel 5: write output ----------------
__global__ void k_out(const float* __restrict__ dets, const int* __restrict__ rank,
                      const u64* __restrict__ remv, float* __restrict__ out, int n) {
    int idx = blockIdx.x * blockDim.x + threadIdx.x;
    if (idx >= n * 5) return;
    int i = idx / 5;
    int r = rank[i];
    u64 w = remv[r >> 6];
    float keep = ((w >> (r & 63)) & 1ULL) ? 0.0f : 1.0f;
    out[idx] = dets[idx] * keep;
}

extern "C" void kernel_launch(void* const* d_in, const int* in_sizes, int n_in,
                              void* d_out, int out_size, void* d_ws, size_t ws_size,
                              hipStream_t stream) {
    const float* dets = (const float*)d_in[0];
    const float* thrp = (const float*)d_in[1];
    int n  = in_sizes[0] / 5;
    int nw = (n + 63) / 64;

    char* ws = (char*)d_ws;
    size_t off = 0;
    u64* diag  = (u64*)(ws + off); off += (size_t)n * sizeof(u64);
    u32* ent   = (u32*)(ws + off); off += (size_t)128 * ENT_CAP * sizeof(u32);
    int* cnt   = (int*)(ws + off); off += 128 * sizeof(int);
    float* sc    = (float*)(ws + off); off += (size_t)n * sizeof(float);
    int*   rank  = (int*)  (ws + off); off += (size_t)n * sizeof(int);
    float* sx1   = (float*)(ws + off); off += (size_t)n * sizeof(float);
    float* sy1   = (float*)(ws + off); off += (size_t)n * sizeof(float);
    float* sx2   = (float*)(ws + off); off += (size_t)n * sizeof(float);
    float* sy2   = (float*)(ws + off); off += (size_t)n * sizeof(float);
    float* sarea = (float*)(ws + off); off += (size_t)n * sizeof(float);
    u64* remv    = (u64*)  (ws + off); off += (size_t)nw * sizeof(u64);

    float* out = (float*)d_out;

    k_scores<<<(n + 255) / 256, 256, 0, stream>>>(dets, sc, cnt, n);
    k_rank<<<(n * 64 + 255) / 256, 256, 0, stream>>>(dets, sc, rank, sx1, sy1, sx2, sy2, sarea, n);
    k_mask<<<nw * nw, 64, 0, stream>>>(sx1, sy1, sx2, sy2, sarea, thrp, diag, ent, cnt, n, nw);
    k_scan<<<1, 256, 0, stream>>>(diag, ent, cnt, remv, n, nw);
    k_out<<<(n * 5 + 255) / 256, 256, 0, stream>>>(dets, rank, remv, out, n);
}

// Round 6
// 121.576 us; speedup vs baseline: 18.7749x; 1.3760x over previous
//
#include <hip/hip_runtime.h>
#include <stdint.h>

typedef unsigned long long u64;
typedef unsigned int u32;

#define ENT_CAP 16384      // entries per 64-row block: 128*16384*4 = 8 MB

// ---------------- kernel 1: extract scores + zero entry counters ----------------
__global__ void k_scores(const float* __restrict__ dets, float* __restrict__ sc,
                         int* __restrict__ cnt, int n) {
    int i = blockIdx.x * blockDim.x + threadIdx.x;
    if (i < n) sc[i] = dets[i * 5 + 4];
    if (i < 128) cnt[i] = 0;
}

// ---------------- kernel 2: rank (counting sort) + scatter sorted boxes ----------------
// one wave (64 lanes) per box i; float4-vectorized score reads
__global__ void k_rank(const float* __restrict__ dets, const float* __restrict__ sc,
                       int* __restrict__ rank,
                       float* __restrict__ sx1, float* __restrict__ sy1,
                       float* __restrict__ sx2, float* __restrict__ sy2,
                       float* __restrict__ sarea, int n) {
    int gid  = blockIdx.x * blockDim.x + threadIdx.x;
    int wave = gid >> 6;
    int lane = threadIdx.x & 63;
    if (wave >= n) return;
    int i = wave;
    float si = sc[i];
    int cnt = 0;
    int n4 = n >> 2;
    const float4* sc4 = (const float4*)sc;
    for (int j4 = lane; j4 < n4; j4 += 64) {
        float4 v = sc4[j4];
        int j = j4 * 4;
        cnt += (v.x > si) || (v.x == si && (j + 0) < i);
        cnt += (v.y > si) || (v.y == si && (j + 1) < i);
        cnt += (v.z > si) || (v.z == si && (j + 2) < i);
        cnt += (v.w > si) || (v.w == si && (j + 3) < i);
    }
    for (int j = (n4 << 2) + lane; j < n; j += 64) {   // tail (n%4 != 0)
        float sj = sc[j];
        cnt += (sj > si) || (sj == si && j < i);
    }
    for (int off = 32; off > 0; off >>= 1) cnt += __shfl_down(cnt, off, 64);
    if (lane == 0) {
        int r = cnt;
        rank[i] = r;
        float x1 = dets[i * 5 + 0], y1 = dets[i * 5 + 1];
        float x2 = dets[i * 5 + 2], y2 = dets[i * 5 + 3];
        sx1[r] = x1; sy1[r] = y1; sx2[r] = x2; sy2[r] = y2;
        sarea[r] = (x2 - x1 + 1.0f) * (y2 - y1 + 1.0f);
    }
}

// ---------------- kernel 3: sparse suppression graph ----------------
// diag[i]   : 64x64 in-block conflict bits (j>i only) for row-block i/64
// ent[b][.] : (k<<16 | j) conflict entries, k = row local to block b, j global col
__global__ void k_mask(const float* __restrict__ sx1, const float* __restrict__ sy1,
                       const float* __restrict__ sx2, const float* __restrict__ sy2,
                       const float* __restrict__ sarea, const float* __restrict__ thrp,
                       u64* __restrict__ diag, u32* __restrict__ ent, int* __restrict__ cnt,
                       int n, int nw) {
    int b  = blockIdx.x;
    int by = b / nw, bx = b % nw;
    if (bx < by) return;                 // lower triangle: nothing to do
    int k  = threadIdx.x;                // 0..63
    int i  = by * 64 + k;                // global row

    __shared__ float cx1[64], cy1[64], cx2[64], cy2[64], ca[64];
    int j0 = bx * 64;
    cx1[k] = sx1[j0 + k]; cy1[k] = sy1[j0 + k];
    cx2[k] = sx2[j0 + k]; cy2[k] = sy2[j0 + k];
    ca[k]  = sarea[j0 + k];
    __syncthreads();

    float x1 = sx1[i], y1 = sy1[i], x2 = sx2[i], y2 = sy2[i], ar = sarea[i];
    float thr = *thrp;
    u64 word = 0ULL;
    #pragma unroll 8
    for (int jj = 0; jj < 64; ++jj) {
        float xx1 = fmaxf(x1, cx1[jj]);
        float yy1 = fmaxf(y1, cy1[jj]);
        float xx2 = fminf(x2, cx2[jj]);
        float yy2 = fminf(y2, cy2[jj]);
        float w = fmaxf(xx2 - xx1 + 1.0f, 0.0f);
        float h = fmaxf(yy2 - yy1 + 1.0f, 0.0f);
        float inter = w * h;
        float iou = inter / (ar + ca[jj] - inter);   // same op order as reference
        word |= ((u64)(iou > thr)) << jj;
    }

    if (bx == by) {
        word &= ~((2ULL << k) - 1ULL);   // keep only j > i
        diag[i] = word;                  // always write (replay-safe)
        return;
    }
    if (__ballot(word != 0ULL) == 0ULL) return;   // whole block conflict-free
    int pc = __popcll(word);
    if (pc) {
        int base = atomicAdd(&cnt[by], pc);
        u32* dst = ent + (size_t)by * ENT_CAP;
        u64 ww = word;
        int x = 0;
        while (ww) {
            int jj = __builtin_ctzll(ww); ww &= ww - 1;
            int idx = base + x;
            if (idx < ENT_CAP) dst[idx] = ((u32)k << 16) | (u32)(j0 + jj);
            ++x;
        }
    }
}

// ---------------- helper: readlane of a u64 (uniform runtime lane index) ----------------
__device__ __forceinline__ u64 readlane_u64(u64 v, int lane) {
    unsigned lo = (unsigned)__builtin_amdgcn_readlane((int)(v & 0xffffffffu), lane);
    unsigned hi = (unsigned)__builtin_amdgcn_readlane((int)(v >> 32), lane);
    return ((u64)hi << 32) | lo;
}

// ---------------- kernel 4: sparse greedy scan — SINGLE WAVE, barrier-free ----------------
// Wave-synchronous: no __syncthreads anywhere. lds_remv ordering between the
// atomicOr scatter of block b and the read at block b+1 comes from the
// compiler's lgkmcnt wait (same wave, LDS ops ordered).
__launch_bounds__(64, 1)
__global__ void k_scan(const u64* __restrict__ diag, const u32* __restrict__ ent,
                       const int* __restrict__ cnt, u64* __restrict__ remv,
                       int n, int nw) {
    __shared__ u64 lds_remv[128];
    int lane = threadIdx.x;
    lds_remv[lane] = 0ULL;
    lds_remv[64 + lane] = 0ULL;

    // preload all 128 per-block entry counts into 2 VGPRs
    int cnt0 = cnt[lane];
    int cnt1 = cnt[64 + lane];

    // prefetch block 0: diag row + first 128 entries
    u64 dreg = (lane < nw * 64 / 64 * 64 || true) ? diag[lane] : 0ULL;
    u32 e0 = ent[lane];
    u32 e1 = ent[64 + lane];

    for (int b = 0; b < nw; ++b) {
        // ---- prefetch next block (hidden under this block's processing) ----
        u64 dnext = 0ULL; u32 f0 = 0, f1 = 0;
        if (b + 1 < nw) {
            dnext = diag[(size_t)(b + 1) * 64 + lane];
            const u32* seg = ent + (size_t)(b + 1) * ENT_CAP;
            f0 = seg[lane];
            f1 = seg[64 + lane];
        }

        int cbv = (b < 64) ? cnt0 : cnt1;
        int cb  = __builtin_amdgcn_readlane(cbv, b & 63);
        if (cb > ENT_CAP) cb = ENT_CAP;
        u64 nz = __ballot(dreg != 0ULL);           // rows with in-block conflicts

        if ((nz | (u64)cb) != 0ULL) {              // skip zero-work blocks entirely
            u64 w = lds_remv[b];                   // broadcast read; waits prior atomicOrs
            if (nz & ~w) {
                u64 avail = ~w & nz;
                while (avail) {                     // ascending greedy over alive rows
                    int k = __builtin_ctzll(avail);
                    w |= readlane_u64(dreg, k);
                    avail &= ~(w | (1ULL << k));
                }
                if (lane == 0) lds_remv[b] = w;
            }
            // ---- scatter alive rows' entries (first 128 prefetched) ----
            if (lane < cb) {
                int k = e0 >> 16, j = e0 & 0xffff;
                if (!((w >> k) & 1ULL)) atomicOr(&lds_remv[j >> 6], 1ULL << (j & 63));
            }
            if (64 + lane < cb) {
                int k = e1 >> 16, j = e1 & 0xffff;
                if (!((w >> k) & 1ULL)) atomicOr(&lds_remv[j >> 6], 1ULL << (j & 63));
            }
            for (int idx = 128 + lane; idx < cb; idx += 64) {   // rare heavy blocks
                u32 e = ent[(size_t)b * ENT_CAP + idx];
                int k = e >> 16, j = e & 0xffff;
                if (!((w >> k) & 1ULL)) atomicOr(&lds_remv[j >> 6], 1ULL << (j & 63));
            }
        }
        dreg = dnext; e0 = f0; e1 = f1;
    }

    if (lane < nw) remv[lane] = lds_remv[lane];
    if (64 + lane < nw) remv[64 + lane] = lds_remv[64 + lane];
}

// ---------------- kernel 5: write output ----------------
__global__ void k_out(const float* __restrict__ dets, const int* __restrict__ rank,
                      const u64* __restrict__ remv, float* __restrict__ out, int n) {
    int idx = blockIdx.x * blockDim.x + threadIdx.x;
    if (idx >= n * 5) return;
    int i = idx / 5;
    int r = rank[i];
    u64 w = remv[r >> 6];
    float keep = ((w >> (r & 63)) & 1ULL) ? 0.0f : 1.0f;
    out[idx] = dets[idx] * keep;
}

extern "C" void kernel_launch(void* const* d_in, const int* in_sizes, int n_in,
                              void* d_out, int out_size, void* d_ws, size_t ws_size,
                              hipStream_t stream) {
    const float* dets = (const float*)d_in[0];
    const float* thrp = (const float*)d_in[1];
    int n  = in_sizes[0] / 5;
    int nw = (n + 63) / 64;

    char* ws = (char*)d_ws;
    size_t off = 0;
    u64* diag  = (u64*)(ws + off); off += (size_t)n * sizeof(u64);
    u32* ent   = (u32*)(ws + off); off += (size_t)128 * ENT_CAP * sizeof(u32);
    int* cnt   = (int*)(ws + off); off += 128 * sizeof(int);
    float* sc    = (float*)(ws + off); off += (size_t)n * sizeof(float);
    int*   rank  = (int*)  (ws + off); off += (size_t)n * sizeof(int);
    float* sx1   = (float*)(ws + off); off += (size_t)n * sizeof(float);
    float* sy1   = (float*)(ws + off); off += (size_t)n * sizeof(float);
    float* sx2   = (float*)(ws + off); off += (size_t)n * sizeof(float);
    float* sy2   = (float*)(ws + off); off += (size_t)n * sizeof(float);
    float* sarea = (float*)(ws + off); off += (size_t)n * sizeof(float);
    u64* remv    = (u64*)  (ws + off); off += (size_t)nw * sizeof(u64);

    float* out = (float*)d_out;

    k_scores<<<(n + 255) / 256, 256, 0, stream>>>(dets, sc, cnt, n);
    k_rank<<<(n * 64 + 255) / 256, 256, 0, stream>>>(dets, sc, rank, sx1, sy1, sx2, sy2, sarea, n);
    k_mask<<<nw * nw, 64, 0, stream>>>(sx1, sy1, sx2, sy2, sarea, thrp, diag, ent, cnt, n, nw);
    k_scan<<<1, 64, 0, stream>>>(diag, ent, cnt, remv, n, nw);
    k_out<<<(n * 5 + 255) / 256, 256, 0, stream>>>(dets, rank, remv, out, n);
}

// Round 7
// 118.101 us; speedup vs baseline: 19.3273x; 1.0294x over previous
//
#include <hip/hip_runtime.h>
#include <stdint.h>
#include <math.h>

typedef unsigned long long u64;
typedef unsigned int u32;

#define ENT_CAP  8192       // per-row-block capacity (fallback layout only)
#define GCAP     65536      // compact global entry capacity
#define LDSE_CAP 24576      // LDS-staged entry capacity (96 KB)

// ---------------- kernel 1: extract scores + zero counters ----------------
__global__ void k_scores(const float* __restrict__ dets, float* __restrict__ sc,
                         int* __restrict__ cnt, int n) {
    int i = blockIdx.x * blockDim.x + threadIdx.x;
    if (i < n) sc[i] = dets[i * 5 + 4];
    if (i < 129) cnt[i] = 0;      // 128 per-block counters + 1 global total
}

// ---------------- kernel 2: rank (counting sort) + scatter sorted boxes ----------------
__global__ void k_rank(const float* __restrict__ dets, const float* __restrict__ sc,
                       int* __restrict__ rank,
                       float* __restrict__ sx1, float* __restrict__ sy1,
                       float* __restrict__ sx2, float* __restrict__ sy2,
                       float* __restrict__ sarea, int n) {
    int gid  = blockIdx.x * blockDim.x + threadIdx.x;
    int wave = gid >> 6;
    int lane = threadIdx.x & 63;
    if (wave >= n) return;
    int i = wave;
    float si = sc[i];
    int cnt = 0;
    int n4 = n >> 2;
    const float4* sc4 = (const float4*)sc;
    for (int j4 = lane; j4 < n4; j4 += 64) {
        float4 v = sc4[j4];
        int j = j4 * 4;
        cnt += (v.x > si) || (v.x == si && (j + 0) < i);
        cnt += (v.y > si) || (v.y == si && (j + 1) < i);
        cnt += (v.z > si) || (v.z == si && (j + 2) < i);
        cnt += (v.w > si) || (v.w == si && (j + 3) < i);
    }
    for (int j = (n4 << 2) + lane; j < n; j += 64) {
        float sj = sc[j];
        cnt += (sj > si) || (sj == si && j < i);
    }
    for (int off = 32; off > 0; off >>= 1) cnt += __shfl_down(cnt, off, 64);
    if (lane == 0) {
        int r = cnt;
        rank[i] = r;
        float x1 = dets[i * 5 + 0], y1 = dets[i * 5 + 1];
        float x2 = dets[i * 5 + 2], y2 = dets[i * 5 + 3];
        sx1[r] = x1; sy1[r] = y1; sx2[r] = x2; sy2[r] = y2;
        sarea[r] = (x2 - x1 + 1.0f) * (y2 - y1 + 1.0f);
    }
}

// ---------------- kernel 3: sparse suppression graph (triangular grid) ----------------
__global__ void k_mask(const float* __restrict__ sx1, const float* __restrict__ sy1,
                       const float* __restrict__ sx2, const float* __restrict__ sy2,
                       const float* __restrict__ sarea, const float* __restrict__ thrp,
                       u64* __restrict__ diag, u32* __restrict__ entc, u32* __restrict__ ent2,
                       int* __restrict__ cnt, int n, int nw) {
    int t = blockIdx.x;
    // decode upper-triangular (by, bx), row-major: row by has (nw-by) blocks
    double nn = (double)nw + 0.5;
    int by = (int)(nn - sqrt(nn * nn - 2.0 * (double)t));
    if (by < 0) by = 0; if (by > nw - 1) by = nw - 1;
    while (by + 1 <= nw - 1 && ((by + 1) * nw - ((by + 1) * by) / 2) <= t) ++by;
    while ((by * nw - (by * (by - 1)) / 2) > t) --by;
    int bx = by + (t - (by * nw - (by * (by - 1)) / 2));

    int k  = threadIdx.x;                // 0..63
    int i  = by * 64 + k;                // global row

    __shared__ float cx1[64], cy1[64], cx2[64], cy2[64], ca[64];
    int j0 = bx * 64;
    cx1[k] = sx1[j0 + k]; cy1[k] = sy1[j0 + k];
    cx2[k] = sx2[j0 + k]; cy2[k] = sy2[j0 + k];
    ca[k]  = sarea[j0 + k];
    __syncthreads();

    float x1 = sx1[i], y1 = sy1[i], x2 = sx2[i], y2 = sy2[i], ar = sarea[i];
    float thr = *thrp;
    u64 word = 0ULL;
    #pragma unroll 8
    for (int jj = 0; jj < 64; ++jj) {
        float xx1 = fmaxf(x1, cx1[jj]);
        float yy1 = fmaxf(y1, cy1[jj]);
        float xx2 = fminf(x2, cx2[jj]);
        float yy2 = fminf(y2, cy2[jj]);
        float w = fmaxf(xx2 - xx1 + 1.0f, 0.0f);
        float h = fmaxf(yy2 - yy1 + 1.0f, 0.0f);
        float inter = w * h;
        float iou = inter / (ar + ca[jj] - inter);   // same op order as reference
        word |= ((u64)(iou > thr)) << jj;
    }

    if (bx == by) {
        word &= ~((2ULL << k) - 1ULL);   // keep only j > i
        diag[i] = word;
        return;
    }
    if (__ballot(word != 0ULL) == 0ULL) return;   // whole block conflict-free
    int pc = __popcll(word);
    if (pc) {
        int base2 = atomicAdd(&cnt[by], pc);       // per-block (fallback layout)
        int baseg = atomicAdd(&cnt[128], pc);      // compact global array
        u64 ww = word;
        int x = 0;
        while (ww) {
            int jj = __builtin_ctzll(ww); ww &= ww - 1;
            int j = j0 + jj;
            if (base2 + x < ENT_CAP)
                ent2[(size_t)by * ENT_CAP + base2 + x] = ((u32)k << 16) | (u32)j;
            if (n <= 8192 && baseg + x < GCAP)
                entc[baseg + x] = ((u32)by << 19) | ((u32)k << 13) | (u32)j;
            ++x;
        }
    }
}

// ---------------- helper: readlane of a u64 (uniform runtime lane index) ----------------
__device__ __forceinline__ u64 readlane_u64(u64 v, int lane) {
    unsigned lo = (unsigned)__builtin_amdgcn_readlane((int)(v & 0xffffffffu), lane);
    unsigned hi = (unsigned)__builtin_amdgcn_readlane((int)(v >> 32), lane);
    return ((u64)hi << 32) | lo;
}

// ---------------- kernel 4: sparse greedy scan — single wave, all-LDS hot loop ----------------
__launch_bounds__(64, 1)
__global__ void k_scan(const u64* __restrict__ diag, const u32* __restrict__ entc,
                       const u32* __restrict__ ent2, const int* __restrict__ cnt,
                       u64* __restrict__ remv, int n, int nw) {
    extern __shared__ char smem[];
    u64* lds_remv = (u64*)smem;                 // 128 u64
    int* lds_cur  = (int*)(smem + 1024);        // 128 int
    u32* lds_ent  = (u32*)(smem + 1536);        // LDSE_CAP u32

    int lane = threadIdx.x;
    lds_remv[lane] = 0ULL;
    lds_remv[64 + lane] = 0ULL;

    int c0 = cnt[lane];
    int c1 = cnt[64 + lane];
    int S  = cnt[128];

    // exclusive prefix offsets over 128 counts (wave-parallel scan, no memory)
    int s0 = c0;
    #pragma unroll
    for (int d = 1; d < 64; d <<= 1) { int tv = __shfl_up(s0, d, 64); if (lane >= d) s0 += tv; }
    int tot0 = __builtin_amdgcn_readlane(s0, 63);
    int s1 = c1;
    #pragma unroll
    for (int d = 1; d < 64; d <<= 1) { int tv = __shfl_up(s1, d, 64); if (lane >= d) s1 += tv; }
    int o0 = s0 - c0;
    int o1 = tot0 + s1 - c1;

    bool fast = (S <= LDSE_CAP) && (n <= 8192);

    if (fast) {
        lds_cur[lane] = o0;
        lds_cur[64 + lane] = o1;
        // stage all S compact entries into LDS, bucketed by block.
        // 16 entries per lane per round via 4x uint4 (one waitcnt per 1024 entries)
        for (int g0 = 0; g0 < S; g0 += 1024) {
            int base = g0 + lane * 16;
            uint4 v0 = *(const uint4*)(entc + base);
            uint4 v1 = *(const uint4*)(entc + base + 4);
            uint4 v2 = *(const uint4*)(entc + base + 8);
            uint4 v3 = *(const uint4*)(entc + base + 12);
            u32 ee[16] = { v0.x, v0.y, v0.z, v0.w, v1.x, v1.y, v1.z, v1.w,
                           v2.x, v2.y, v2.z, v2.w, v3.x, v3.y, v3.z, v3.w };
            #pragma unroll
            for (int u = 0; u < 16; ++u) {
                if (base + u < S) {
                    u32 e = ee[u];
                    int b = e >> 19;
                    int pos = atomicAdd(&lds_cur[b], 1);
                    lds_ent[pos] = e;
                }
            }
        }
    }

    // 4-deep register prefetch of diag rows (only global access in the loop)
    u64 d0 = (0 < nw) ? diag[(size_t)0 * 64 + lane] : 0ULL;
    u64 d1 = (1 < nw) ? diag[(size_t)1 * 64 + lane] : 0ULL;
    u64 d2 = (2 < nw) ? diag[(size_t)2 * 64 + lane] : 0ULL;
    u64 d3 = (3 < nw) ? diag[(size_t)3 * 64 + lane] : 0ULL;

    for (int b = 0; b < nw; ++b) {
        u64 dn = (b + 4 < nw) ? diag[(size_t)(b + 4) * 64 + lane] : 0ULL;
        int cb = __builtin_amdgcn_readlane((b < 64) ? c0 : c1, b & 63);
        int ob = __builtin_amdgcn_readlane((b < 64) ? o0 : o1, b & 63);
        u64 nz = __ballot(d0 != 0ULL);

        if ((nz | (u64)(u32)cb) != 0ULL) {
            u64 w = lds_remv[b];               // sees all prior atomicOrs (same wave)
            if (nz & ~w) {
                u64 avail = ~w & nz;
                while (avail) {                // ascending greedy over alive rows
                    int k = __builtin_ctzll(avail);
                    w |= readlane_u64(d0, k);
                    avail &= ~(w | (1ULL << k));
                }
                if (lane == 0) lds_remv[b] = w;
            }
            if (fast) {
                for (int idx = lane; idx < cb; idx += 64) {
                    u32 e = lds_ent[ob + idx];
                    int k = (e >> 13) & 63, j = e & 8191;
                    if (!((w >> k) & 1ULL)) atomicOr(&lds_remv[j >> 6], 1ULL << (j & 63));
                }
            } else {
                int cbl = (cb < ENT_CAP) ? cb : ENT_CAP;
                for (int idx = lane; idx < cbl; idx += 64) {
                    u32 e = ent2[(size_t)b * ENT_CAP + idx];
                    int k = e >> 16, j = e & 0xffff;
                    if (!((w >> k) & 1ULL)) atomicOr(&lds_remv[j >> 6], 1ULL << (j & 63));
                }
            }
        }
        d0 = d1; d1 = d2; d2 = d3; d3 = dn;
    }

    if (lane < nw) remv[lane] = lds_remv[lane];
    if (64 + lane < nw) remv[64 + lane] = lds_remv[64 + lane];
}

// ---------------- kernel 5: write output ----------------
__global__ void k_out(const float* __restrict__ dets, const int* __restrict__ rank,
                      const u64* __restrict__ remv, float* __restrict__ out, int n) {
    int idx = blockIdx.x * blockDim.x + threadIdx.x;
    if (idx >= n * 5) return;
    int i = idx / 5;
    int r = rank[i];
    u64 w = remv[r >> 6];
    float keep = ((w >> (r & 63)) & 1ULL) ? 0.0f : 1.0f;
    out[idx] = dets[idx] * keep;
}

extern "C" void kernel_launch(void* const* d_in, const int* in_sizes, int n_in,
                              void* d_out, int out_size, void* d_ws, size_t ws_size,
                              hipStream_t stream) {
    const float* dets = (const float*)d_in[0];
    const float* thrp = (const float*)d_in[1];
    int n  = in_sizes[0] / 5;
    int nw = (n + 63) / 64;

    char* ws = (char*)d_ws;
    size_t off = 0;
    auto carve = [&](size_t bytes) { char* p = ws + off; off = (off + bytes + 255) & ~(size_t)255; return p; };
    u64* diag  = (u64*)carve((size_t)n * sizeof(u64));
    u32* entc  = (u32*)carve((size_t)GCAP * sizeof(u32));
    u32* ent2  = (u32*)carve((size_t)128 * ENT_CAP * sizeof(u32));
    int* cnt   = (int*)carve(129 * sizeof(int));
    float* sc    = (float*)carve((size_t)n * sizeof(float));
    int*   rank  = (int*)  carve((size_t)n * sizeof(int));
    float* sx1   = (float*)carve((size_t)n * sizeof(float));
    float* sy1   = (float*)carve((size_t)n * sizeof(float));
    float* sx2   = (float*)carve((size_t)n * sizeof(float));
    float* sy2   = (float*)carve((size_t)n * sizeof(float));
    float* sarea = (float*)carve((size_t)n * sizeof(float));
    u64* remv    = (u64*)  carve((size_t)nw * sizeof(u64));

    float* out = (float*)d_out;

    int tri = nw * (nw + 1) / 2;
    int scan_lds = 1024 + 512 + LDSE_CAP * 4;

    k_scores<<<(n + 255) / 256, 256, 0, stream>>>(dets, sc, cnt, n);
    k_rank<<<(n * 64 + 255) / 256, 256, 0, stream>>>(dets, sc, rank, sx1, sy1, sx2, sy2, sarea, n);
    k_mask<<<tri, 64, 0, stream>>>(sx1, sy1, sx2, sy2, sarea, thrp, diag, entc, ent2, cnt, n, nw);
    k_scan<<<1, 64, scan_lds, stream>>>(diag, entc, ent2, cnt, remv, n, nw);
    k_out<<<(n * 5 + 255) / 256, 256, 0, stream>>>(dets, rank, remv, out, n);
}